// Round 4
// baseline (299.371 us; speedup 1.0000x reference)
//
#include <hip/hip_runtime.h>

// Trilinear interpolation of a 128^3 x 16 latent grid at 2M points.
// Two-phase spatially-binned version: random point order gives zero L2
// locality (134 MB table vs 4 MB/XCD L2), so phase A bins points by coarse
// spatial cell (16^3 bins, ~512 pts each) and phase B processes one bin per
// block -- the bin's 9^3-row latent footprint (~46 KB) stays L2/L1-hot.

constexpr int GRID_RES   = 128;
constexpr int LATENT_DIM = 16;
constexpr int BINS_AXIS  = 16;                       // cell >> 3
constexpr int NBINS      = BINS_AXIS * BINS_AXIS * BINS_AXIS;  // 4096
constexpr int BIN_CAP    = 1024;                     // mean 512, sigma ~23
constexpr size_t BINS_OFF = 65536;                   // counts region size (aligned)

typedef float fvec4 __attribute__((ext_vector_type(4)));

// ---- shared trilerp helpers -------------------------------------------------

__device__ __forceinline__ void corner_setup(
    float sx, float sy, float sz,
    int cx[2], int cy[2], int cz[2],
    float fx[2], float fy[2], float fz[2])
{
    const float bx = floorf(sx), by = floorf(sy), bz = floorf(sz);
    const int ix = (int)bx, iy = (int)by, iz = (int)bz;
    const float wbx = sx - bx, wby = sy - by, wbz = sz - bz;
    cx[0] = min(max(ix,     0), GRID_RES - 1);
    cx[1] = min(max(ix + 1, 0), GRID_RES - 1);
    cy[0] = min(max(iy,     0), GRID_RES - 1);
    cy[1] = min(max(iy + 1, 0), GRID_RES - 1);
    cz[0] = min(max(iz,     0), GRID_RES - 1);
    cz[1] = min(max(iz + 1, 0), GRID_RES - 1);
    fx[0] = 1.0f - wbx; fx[1] = wbx;
    fy[0] = 1.0f - wby; fy[1] = wby;
    fz[0] = 1.0f - wbz; fz[1] = wbz;
}

// one float4-slice (q of 4) of the 16-dim trilerp
__device__ __forceinline__ fvec4 trilerp_q(
    const float* __restrict__ latents,
    const int cx[2], const int cy[2], const int cz[2],
    const float fx[2], const float fy[2], const float fz[2], int q)
{
    fvec4 acc = (fvec4)(0.0f);
    #pragma unroll
    for (int ox = 0; ox < 2; ++ox)
      #pragma unroll
      for (int oy = 0; oy < 2; ++oy)
        #pragma unroll
        for (int oz = 0; oz < 2; ++oz) {
            const int flat = cx[ox] * (GRID_RES * GRID_RES) + cy[oy] * GRID_RES + cz[oz];
            const float w = fx[ox] * fy[oy] * fz[oz];
            const fvec4 f = *reinterpret_cast<const fvec4*>(
                latents + (size_t)flat * LATENT_DIM + q * 4);
            acc += w * f;
        }
    return acc;
}

// ---- phase A: bin points ----------------------------------------------------

__global__ __launch_bounds__(256) void scatter_kernel(
    const float* __restrict__ pts, int n_pts,
    unsigned* __restrict__ counts, fvec4* __restrict__ bins,
    const float* __restrict__ latents, float* __restrict__ out)
{
    const int p = blockIdx.x * blockDim.x + threadIdx.x;
    if (p >= n_pts) return;

    const float x = pts[3 * p + 0];
    const float y = pts[3 * p + 1];
    const float z = pts[3 * p + 2];

    const float S = (float)(GRID_RES - 2);
    const int lx = min(max((int)floorf(x * S), 0), GRID_RES - 3);
    const int ly = min(max((int)floorf(y * S), 0), GRID_RES - 3);
    const int lz = min(max((int)floorf(z * S), 0), GRID_RES - 3);
    const int bin = ((lx >> 3) << 8) | ((ly >> 3) << 4) | (lz >> 3);

    const unsigned slot = atomicAdd(&counts[bin], 1u);
    if (slot < (unsigned)BIN_CAP) {
        fvec4 t;
        t.x = x; t.y = y; t.z = z;
        t.w = __uint_as_float((unsigned)p);
        bins[(size_t)bin * BIN_CAP + slot] = t;
    } else {
        // statistically impossible overflow (11 sigma) -- compute inline
        int cx[2], cy[2], cz[2]; float fx[2], fy[2], fz[2];
        corner_setup(x * S, y * S, z * S, cx, cy, cz, fx, fy, fz);
        #pragma unroll
        for (int q = 0; q < 4; ++q) {
            const fvec4 acc = trilerp_q(latents, cx, cy, cz, fx, fy, fz, q);
            *reinterpret_cast<fvec4*>(out + (size_t)p * LATENT_DIM + q * 4) = acc;
        }
    }
}

// ---- phase B: one block per bin --------------------------------------------

__global__ __launch_bounds__(256) void binned_trilerp(
    const fvec4* __restrict__ bins, const unsigned* __restrict__ counts,
    const float* __restrict__ latents, float* __restrict__ out)
{
    const int bin = blockIdx.x;
    const unsigned n = min(counts[bin], (unsigned)BIN_CAP);
    const int q     = threadIdx.x & 3;   // which float4 of 16 features
    const int local = threadIdx.x >> 2;  // 0..63 point slot in this pass

    const float S = (float)(GRID_RES - 2);

    for (unsigned base = 0; base < n; base += 64) {
        const unsigned i = base + local;
        if (i < n) {
            const fvec4 t = bins[(size_t)bin * BIN_CAP + i];
            const unsigned idx = __float_as_uint(t.w);

            int cx[2], cy[2], cz[2]; float fx[2], fy[2], fz[2];
            corner_setup(t.x * S, t.y * S, t.z * S, cx, cy, cz, fx, fy, fz);
            const fvec4 acc = trilerp_q(latents, cx, cy, cz, fx, fy, fz, q);

            *reinterpret_cast<fvec4*>(out + (size_t)idx * LATENT_DIM + q * 4) = acc;
        }
    }
}

// ---- fallback (ws too small): direct version --------------------------------

__global__ __launch_bounds__(256) void trilerp_direct(
    const float* __restrict__ pts, const float* __restrict__ latents,
    float* __restrict__ out, int n_pts)
{
    const int tid = blockIdx.x * blockDim.x + threadIdx.x;
    const int p = tid >> 2;
    const int q = tid & 3;
    if (p >= n_pts) return;

    const float S = (float)(GRID_RES - 2);
    int cx[2], cy[2], cz[2]; float fx[2], fy[2], fz[2];
    corner_setup(pts[3*p] * S, pts[3*p+1] * S, pts[3*p+2] * S, cx, cy, cz, fx, fy, fz);
    const fvec4 acc = trilerp_q(latents, cx, cy, cz, fx, fy, fz, q);
    *reinterpret_cast<fvec4*>(out + (size_t)p * LATENT_DIM + q * 4) = acc;
}

// ---- launch -----------------------------------------------------------------

extern "C" void kernel_launch(void* const* d_in, const int* in_sizes, int n_in,
                              void* d_out, int out_size, void* d_ws, size_t ws_size,
                              hipStream_t stream) {
    const float* pts     = (const float*)d_in[0];
    const float* latents = (const float*)d_in[1];
    float* out = (float*)d_out;
    const int n_pts = in_sizes[0] / 3;

    const size_t ws_needed = BINS_OFF + (size_t)NBINS * BIN_CAP * sizeof(fvec4);
    if (ws_size < ws_needed) {
        const int total = n_pts * 4;
        trilerp_direct<<<(total + 255) / 256, 256, 0, stream>>>(pts, latents, out, n_pts);
        return;
    }

    unsigned* counts = (unsigned*)d_ws;
    fvec4*    bins   = (fvec4*)((char*)d_ws + BINS_OFF);

    hipMemsetAsync(counts, 0, NBINS * sizeof(unsigned), stream);
    scatter_kernel<<<(n_pts + 255) / 256, 256, 0, stream>>>(
        pts, n_pts, counts, bins, latents, out);
    binned_trilerp<<<NBINS, 256, 0, stream>>>(bins, counts, latents, out);
}

// Round 5
// 187.115 us; speedup vs baseline: 1.5999x; 1.5999x over previous
//
#include <hip/hip_runtime.h>

// Trilinear interpolation of a 128^3 x 16 latent grid at 2M random points.
// 3-phase spatial counting sort:
//   A1: counting-sort points into 64 super-bins (4^3), segments stored in d_out
//       (fully overwritten by B afterwards).
//   A2: per super-bin, counting-sort its segment into 64 children -> 4096 fine
//       bins (16^3, 8^3 grid cells each) in d_ws.
//   B : one block per fine bin; stage the bin's 9^3-row latent footprint
//       (46.7 KB, bank-swizzled) into LDS; all gathers become LDS reads.
// Spill list + cleanup kernel guard the (>>10 sigma) capacity overflow paths.

constexpr int   GRID_RES   = 128;
constexpr int   LATENT_DIM = 16;
constexpr float SCALE      = 126.0f;          // GRID_RES - 2

constexpr int NSUPER    = 64;                  // 4x4x4
constexpr int NFINE     = 4096;                // 16x16x16
constexpr int CAP_F     = 768;                 // mean 512, sigma ~22.6
constexpr int SPILL_CAP = 16384;

// d_ws layout
constexpr size_t SCUR_OFF     = 0;             // 64 u32
constexpr size_t FCUR_OFF     = 1024;          // 4096 u32
constexpr size_t SPILLCUR_OFF = 20480;         // 1 u32
constexpr size_t CUR_BYTES    = 32768;         // memset region
constexpr size_t FINE_OFF     = CUR_BYTES;
constexpr size_t FINE_BYTES   = (size_t)NFINE * CAP_F * 16;
constexpr size_t SPILL_OFF    = FINE_OFF + FINE_BYTES;
constexpr size_t WS_NEEDED    = SPILL_OFF + (size_t)SPILL_CAP * 16;

typedef float fvec4 __attribute__((ext_vector_type(4)));

// ---- helpers ----------------------------------------------------------------

__device__ __forceinline__ void fine_bin(float x, float y, float z,
                                         int* s, int* c) {
    const int lx = min(max((int)floorf(x * SCALE), 0), 125);
    const int ly = min(max((int)floorf(y * SCALE), 0), 125);
    const int lz = min(max((int)floorf(z * SCALE), 0), 125);
    const int fbx = lx >> 3, fby = ly >> 3, fbz = lz >> 3;  // [0,16)
    *s = ((fbx >> 2) << 4) | ((fby >> 2) << 2) | (fbz >> 2);
    *c = ((fbx & 3) << 4) | ((fby & 3) << 2) | (fbz & 3);
}

__device__ __forceinline__ void corner_setup(
    float sx, float sy, float sz,
    int cx[2], int cy[2], int cz[2],
    float fx[2], float fy[2], float fz[2])
{
    const float bx = floorf(sx), by = floorf(sy), bz = floorf(sz);
    const int ix = (int)bx, iy = (int)by, iz = (int)bz;
    const float wbx = sx - bx, wby = sy - by, wbz = sz - bz;
    cx[0] = min(max(ix,     0), GRID_RES - 1);
    cx[1] = min(max(ix + 1, 0), GRID_RES - 1);
    cy[0] = min(max(iy,     0), GRID_RES - 1);
    cy[1] = min(max(iy + 1, 0), GRID_RES - 1);
    cz[0] = min(max(iz,     0), GRID_RES - 1);
    cz[1] = min(max(iz + 1, 0), GRID_RES - 1);
    fx[0] = 1.0f - wbx; fx[1] = wbx;
    fy[0] = 1.0f - wby; fy[1] = wby;
    fz[0] = 1.0f - wbz; fz[1] = wbz;
}

__device__ __forceinline__ fvec4 trilerp_q(
    const float* __restrict__ latents,
    const int cx[2], const int cy[2], const int cz[2],
    const float fx[2], const float fy[2], const float fz[2], int q)
{
    fvec4 acc = (fvec4)(0.0f);
    #pragma unroll
    for (int ox = 0; ox < 2; ++ox)
      #pragma unroll
      for (int oy = 0; oy < 2; ++oy)
        #pragma unroll
        for (int oz = 0; oz < 2; ++oz) {
            const int flat = cx[ox] * (GRID_RES * GRID_RES) + cy[oy] * GRID_RES + cz[oz];
            const float w = fx[ox] * fy[oy] * fz[oz];
            const fvec4 f = *reinterpret_cast<const fvec4*>(
                latents + (size_t)flat * LATENT_DIM + q * 4);
            acc += w * f;
        }
    return acc;
}

// ---- A1: counting-sort into 64 super-bins (segments in d_out) ---------------

__global__ __launch_bounds__(256) void binA1(
    const float* __restrict__ pts, int n_pts,
    unsigned* __restrict__ scur, fvec4* __restrict__ superSeg, int cap_s,
    unsigned* __restrict__ spillcur, fvec4* __restrict__ spillSeg)
{
    __shared__ unsigned cnt[NSUPER], base[NSUPER], off[NSUPER];
    const int t = threadIdx.x;
    if (t < NSUPER) { cnt[t] = 0; off[t] = 0; }
    __syncthreads();

    const int chunk = (n_pts + gridDim.x - 1) / gridDim.x;
    const int lo = blockIdx.x * chunk;
    const int hi = min(lo + chunk, n_pts);

    for (int p = lo + t; p < hi; p += 256) {
        int s, c;
        fine_bin(pts[3*p], pts[3*p+1], pts[3*p+2], &s, &c);
        atomicAdd(&cnt[s], 1u);
    }
    __syncthreads();
    if (t < NSUPER) base[t] = atomicAdd(&scur[t], cnt[t]);
    __syncthreads();
    for (int p = lo + t; p < hi; p += 256) {
        const float x = pts[3*p], y = pts[3*p+1], z = pts[3*p+2];
        int s, c;
        fine_bin(x, y, z, &s, &c);
        const unsigned slot = base[s] + atomicAdd(&off[s], 1u);
        fvec4 tp; tp.x = x; tp.y = y; tp.z = z; tp.w = __uint_as_float((unsigned)p);
        if (slot < (unsigned)cap_s) {
            superSeg[(size_t)s * cap_s + slot] = tp;
        } else {                                   // ~impossible; keep correct
            const unsigned sp = atomicAdd(spillcur, 1u);
            if (sp < (unsigned)SPILL_CAP) spillSeg[sp] = tp;
        }
    }
}

// ---- A2: refine each super-bin into its 64 children -------------------------

__global__ __launch_bounds__(256) void binA2(
    const fvec4* __restrict__ superSeg, int cap_s,
    const unsigned* __restrict__ scur,
    unsigned* __restrict__ fcur, fvec4* __restrict__ fineSeg,
    unsigned* __restrict__ spillcur, fvec4* __restrict__ spillSeg)
{
    constexpr int SLICES = 8;
    const int super = blockIdx.x / SLICES;
    const int slice = blockIdx.x % SLICES;
    const unsigned n = min(scur[super], (unsigned)cap_s);
    const unsigned lo = (unsigned)(((unsigned long long)n * slice) / SLICES);
    const unsigned hi = (unsigned)(((unsigned long long)n * (slice + 1)) / SLICES);

    __shared__ unsigned cnt[64], base[64], off[64];
    const int t = threadIdx.x;
    if (t < 64) { cnt[t] = 0; off[t] = 0; }
    __syncthreads();

    for (unsigned i = lo + t; i < hi; i += 256) {
        const fvec4 tp = superSeg[(size_t)super * cap_s + i];
        int s, c;
        fine_bin(tp.x, tp.y, tp.z, &s, &c);
        atomicAdd(&cnt[c], 1u);
    }
    __syncthreads();
    if (t < 64) base[t] = atomicAdd(&fcur[super * 64 + t], cnt[t]);
    __syncthreads();
    for (unsigned i = lo + t; i < hi; i += 256) {
        const fvec4 tp = superSeg[(size_t)super * cap_s + i];
        int s, c;
        fine_bin(tp.x, tp.y, tp.z, &s, &c);
        const unsigned slot = base[c] + atomicAdd(&off[c], 1u);
        if (slot < (unsigned)CAP_F) {
            fineSeg[(size_t)(super * 64 + c) * CAP_F + slot] = tp;
        } else {
            const unsigned sp = atomicAdd(spillcur, 1u);
            if (sp < (unsigned)SPILL_CAP) spillSeg[sp] = tp;
        }
    }
}

// ---- B: per-fine-bin trilerp with LDS-staged latent footprint ---------------

__global__ __launch_bounds__(256) void binB(
    const fvec4* __restrict__ fineSeg, const unsigned* __restrict__ fcur,
    const float* __restrict__ latents, float* __restrict__ out)
{
    __shared__ __align__(16) float lat[729 * 16];   // 46.7 KB, 9x9x9 rows

    const int fid = blockIdx.x;
    const int super = fid >> 6, c = fid & 63;
    const int bx = ((super >> 4) << 2)        | (c >> 4);
    const int by = ((((super >> 2) & 3)) << 2) | ((c >> 2) & 3);
    const int bz = ((super & 3) << 2)         | (c & 3);
    const int t = threadIdx.x;

    // stage rows [8b .. 8b+8]^3 (clamped at 127; clamp rows never read)
    for (int u = t; u < 729 * 4; u += 256) {
        const int q4 = u & 3, r = u >> 2;
        const int dz = r % 9, t2 = r / 9, dy = t2 % 9, dx = t2 / 9;
        const int gx = min(bx * 8 + dx, 127);
        const int gy = min(by * 8 + dy, 127);
        const int gz = min(bz * 8 + dz, 127);
        const fvec4 v = *reinterpret_cast<const fvec4*>(
            latents + ((size_t)(((gx << 7) | gy) << 7 | gz)) * LATENT_DIM + q4 * 4);
        const int sw = (q4 + r + (r >> 2)) & 3;     // bank swizzle
        *reinterpret_cast<fvec4*>(&lat[r * 16 + sw * 4]) = v;
    }
    __syncthreads();

    const unsigned n = min(fcur[fid], (unsigned)CAP_F);
    const int q = t & 3, lp = t >> 2;

    for (unsigned i = lp; i < n; i += 64) {
        const fvec4 tp = fineSeg[(size_t)fid * CAP_F + i];
        const unsigned idx = __float_as_uint(tp.w);

        const float sxv = tp.x * SCALE, syv = tp.y * SCALE, szv = tp.z * SCALE;
        const float bxf = floorf(sxv), byf = floorf(syv), bzf = floorf(szv);
        const int lx = (int)bxf - bx * 8;           // in [0,8]
        const int ly = (int)byf - by * 8;
        const int lz = (int)bzf - bz * 8;
        const float wbx = sxv - bxf, wby = syv - byf, wbz = szv - bzf;
        const float fx[2] = {1.0f - wbx, wbx};
        const float fy[2] = {1.0f - wby, wby};
        const float fz[2] = {1.0f - wbz, wbz};

        fvec4 acc = (fvec4)(0.0f);
        #pragma unroll
        for (int ox = 0; ox < 2; ++ox)
          #pragma unroll
          for (int oy = 0; oy < 2; ++oy)
            #pragma unroll
            for (int oz = 0; oz < 2; ++oz) {
                const int r = (lx + ox) * 81 + (ly + oy) * 9 + (lz + oz);
                const int sw = (q + r + (r >> 2)) & 3;
                const fvec4 f = *reinterpret_cast<const fvec4*>(&lat[r * 16 + sw * 4]);
                acc += (fx[ox] * fy[oy] * fz[oz]) * f;
            }

        *reinterpret_cast<fvec4*>(out + (size_t)idx * LATENT_DIM + q * 4) = acc;
    }
}

// ---- spill cleanup (normally n == 0) ----------------------------------------

__global__ __launch_bounds__(256) void spillK(
    const fvec4* __restrict__ spillSeg, const unsigned* __restrict__ spillcur,
    const float* __restrict__ latents, float* __restrict__ out)
{
    const unsigned n = min(*spillcur, (unsigned)SPILL_CAP);
    for (unsigned i = blockIdx.x * 256 + threadIdx.x; i < n; i += gridDim.x * 256) {
        const fvec4 tp = spillSeg[i];
        const unsigned idx = __float_as_uint(tp.w);
        int cx[2], cy[2], cz[2]; float fx[2], fy[2], fz[2];
        corner_setup(tp.x * SCALE, tp.y * SCALE, tp.z * SCALE, cx, cy, cz, fx, fy, fz);
        #pragma unroll
        for (int q = 0; q < 4; ++q) {
            const fvec4 acc = trilerp_q(latents, cx, cy, cz, fx, fy, fz, q);
            *reinterpret_cast<fvec4*>(out + (size_t)idx * LATENT_DIM + q * 4) = acc;
        }
    }
}

// ---- fallback: direct version ----------------------------------------------

__global__ __launch_bounds__(256) void trilerp_direct(
    const float* __restrict__ pts, const float* __restrict__ latents,
    float* __restrict__ out, int n_pts)
{
    const int tid = blockIdx.x * blockDim.x + threadIdx.x;
    const int p = tid >> 2;
    const int q = tid & 3;
    if (p >= n_pts) return;
    int cx[2], cy[2], cz[2]; float fx[2], fy[2], fz[2];
    corner_setup(pts[3*p] * SCALE, pts[3*p+1] * SCALE, pts[3*p+2] * SCALE,
                 cx, cy, cz, fx, fy, fz);
    const fvec4 acc = trilerp_q(latents, cx, cy, cz, fx, fy, fz, q);
    *reinterpret_cast<fvec4*>(out + (size_t)p * LATENT_DIM + q * 4) = acc;
}

// ---- launch -----------------------------------------------------------------

extern "C" void kernel_launch(void* const* d_in, const int* in_sizes, int n_in,
                              void* d_out, int out_size, void* d_ws, size_t ws_size,
                              hipStream_t stream) {
    const float* pts     = (const float*)d_in[0];
    const float* latents = (const float*)d_in[1];
    float* out = (float*)d_out;
    const int n_pts = in_sizes[0] / 3;

    const int cap_s = (int)(((size_t)out_size * 4) / (NSUPER * 16));  // tuples/super seg

    if (ws_size < WS_NEEDED || cap_s * (size_t)NSUPER * 16 > (size_t)out_size * 4 ||
        (size_t)cap_s < (size_t)n_pts / 16) {
        const int total = n_pts * 4;
        trilerp_direct<<<(total + 255) / 256, 256, 0, stream>>>(pts, latents, out, n_pts);
        return;
    }

    unsigned* scur     = (unsigned*)((char*)d_ws + SCUR_OFF);
    unsigned* fcur     = (unsigned*)((char*)d_ws + FCUR_OFF);
    unsigned* spillcur = (unsigned*)((char*)d_ws + SPILLCUR_OFF);
    fvec4*    fineSeg  = (fvec4*)((char*)d_ws + FINE_OFF);
    fvec4*    spillSeg = (fvec4*)((char*)d_ws + SPILL_OFF);
    fvec4*    superSeg = (fvec4*)d_out;                 // reused as scratch

    hipMemsetAsync(d_ws, 0, CUR_BYTES, stream);
    binA1<<<256, 256, 0, stream>>>(pts, n_pts, scur, superSeg, cap_s,
                                   spillcur, spillSeg);
    binA2<<<NSUPER * 8, 256, 0, stream>>>(superSeg, cap_s, scur,
                                          fcur, fineSeg, spillcur, spillSeg);
    binB<<<NFINE, 256, 0, stream>>>(fineSeg, fcur, latents, out);
    spillK<<<16, 256, 0, stream>>>(spillSeg, spillcur, latents, out);
}

// Round 6
// 163.690 us; speedup vs baseline: 1.8289x; 1.1431x over previous
//
#include <hip/hip_runtime.h>

// Trilinear interpolation of a 128^3 x 16 latent grid at 2M random points.
// 3-phase spatial counting sort:
//   A1: counting-sort points into 64 super-bins (4x4x4), segments in d_out
//       (d_out is fully overwritten by B afterwards).
//   A2: per super-bin, counting-sort its segment into 128 children -> 8192
//       fine bins (16x16x32; 8x8x4 grid cells each) in d_ws.
//   B : one block per fine bin; stage the bin's 9x9x5-row latent footprint
//       (25.9 KB -> 6 blocks/CU, ~75% occupancy) into LDS; gathers = LDS reads.
// Spill list + cleanup kernel guard the (>>8 sigma) capacity overflow paths.

constexpr int   GRID_RES   = 128;
constexpr int   LATENT_DIM = 16;
constexpr float SCALE      = 126.0f;          // GRID_RES - 2

constexpr int NSUPER    = 64;                  // 4x4x4
constexpr int NCHILD    = 128;                 // 4x4x8 per super
constexpr int NFINE     = NSUPER * NCHILD;     // 8192 (16x16x32)
constexpr int CAP_F     = 384;                 // mean 256, sigma ~16
constexpr int SPILL_CAP = 16384;
constexpr int NROWS     = 9 * 9 * 5;           // 405 staged latent rows

// d_ws layout
constexpr size_t SCUR_OFF     = 0;             // 64 u32
constexpr size_t FCUR_OFF     = 1024;          // 8192 u32
constexpr size_t SPILLCUR_OFF = 33792;         // 1 u32
constexpr size_t CUR_BYTES    = 36864;         // memset region
constexpr size_t FINE_OFF     = CUR_BYTES;
constexpr size_t FINE_BYTES   = (size_t)NFINE * CAP_F * 16;
constexpr size_t SPILL_OFF    = FINE_OFF + FINE_BYTES;
constexpr size_t WS_NEEDED    = SPILL_OFF + (size_t)SPILL_CAP * 16;

typedef float fvec4 __attribute__((ext_vector_type(4)));

// ---- helpers ----------------------------------------------------------------

__device__ __forceinline__ void fine_bin(float x, float y, float z,
                                         int* s, int* c) {
    const int lx = min(max((int)floorf(x * SCALE), 0), 125);
    const int ly = min(max((int)floorf(y * SCALE), 0), 125);
    const int lz = min(max((int)floorf(z * SCALE), 0), 125);
    const int fbx = lx >> 3;   // [0,16)
    const int fby = ly >> 3;   // [0,16)
    const int fbz = lz >> 2;   // [0,32)
    *s = ((fbx >> 2) << 4) | ((fby >> 2) << 2) | (fbz >> 3);           // [0,64)
    *c = ((fbx & 3) << 5) | ((fby & 3) << 3) | (fbz & 7);              // [0,128)
}

__device__ __forceinline__ void corner_setup(
    float sx, float sy, float sz,
    int cx[2], int cy[2], int cz[2],
    float fx[2], float fy[2], float fz[2])
{
    const float bx = floorf(sx), by = floorf(sy), bz = floorf(sz);
    const int ix = (int)bx, iy = (int)by, iz = (int)bz;
    const float wbx = sx - bx, wby = sy - by, wbz = sz - bz;
    cx[0] = min(max(ix,     0), GRID_RES - 1);
    cx[1] = min(max(ix + 1, 0), GRID_RES - 1);
    cy[0] = min(max(iy,     0), GRID_RES - 1);
    cy[1] = min(max(iy + 1, 0), GRID_RES - 1);
    cz[0] = min(max(iz,     0), GRID_RES - 1);
    cz[1] = min(max(iz + 1, 0), GRID_RES - 1);
    fx[0] = 1.0f - wbx; fx[1] = wbx;
    fy[0] = 1.0f - wby; fy[1] = wby;
    fz[0] = 1.0f - wbz; fz[1] = wbz;
}

__device__ __forceinline__ fvec4 trilerp_q(
    const float* __restrict__ latents,
    const int cx[2], const int cy[2], const int cz[2],
    const float fx[2], const float fy[2], const float fz[2], int q)
{
    fvec4 acc = (fvec4)(0.0f);
    #pragma unroll
    for (int ox = 0; ox < 2; ++ox)
      #pragma unroll
      for (int oy = 0; oy < 2; ++oy)
        #pragma unroll
        for (int oz = 0; oz < 2; ++oz) {
            const int flat = cx[ox] * (GRID_RES * GRID_RES) + cy[oy] * GRID_RES + cz[oz];
            const float w = fx[ox] * fy[oy] * fz[oz];
            const fvec4 f = *reinterpret_cast<const fvec4*>(
                latents + (size_t)flat * LATENT_DIM + q * 4);
            acc += w * f;
        }
    return acc;
}

// ---- A1: counting-sort into 64 super-bins (segments in d_out) ---------------

__global__ __launch_bounds__(256) void binA1(
    const float* __restrict__ pts, int n_pts,
    unsigned* __restrict__ scur, fvec4* __restrict__ superSeg, int cap_s,
    unsigned* __restrict__ spillcur, fvec4* __restrict__ spillSeg)
{
    __shared__ unsigned cnt[NSUPER], base[NSUPER], off[NSUPER];
    const int t = threadIdx.x;
    if (t < NSUPER) { cnt[t] = 0; off[t] = 0; }
    __syncthreads();

    const int chunk = (n_pts + gridDim.x - 1) / gridDim.x;
    const int lo = blockIdx.x * chunk;
    const int hi = min(lo + chunk, n_pts);

    for (int p = lo + t; p < hi; p += 256) {
        int s, c;
        fine_bin(pts[3*p], pts[3*p+1], pts[3*p+2], &s, &c);
        atomicAdd(&cnt[s], 1u);
    }
    __syncthreads();
    if (t < NSUPER) base[t] = atomicAdd(&scur[t], cnt[t]);
    __syncthreads();
    for (int p = lo + t; p < hi; p += 256) {
        const float x = pts[3*p], y = pts[3*p+1], z = pts[3*p+2];
        int s, c;
        fine_bin(x, y, z, &s, &c);
        const unsigned slot = base[s] + atomicAdd(&off[s], 1u);
        fvec4 tp; tp.x = x; tp.y = y; tp.z = z; tp.w = __uint_as_float((unsigned)p);
        if (slot < (unsigned)cap_s) {
            superSeg[(size_t)s * cap_s + slot] = tp;
        } else {                                   // ~impossible; keep correct
            const unsigned sp = atomicAdd(spillcur, 1u);
            if (sp < (unsigned)SPILL_CAP) spillSeg[sp] = tp;
        }
    }
}

// ---- A2: refine each super-bin into its 128 children ------------------------

__global__ __launch_bounds__(256) void binA2(
    const fvec4* __restrict__ superSeg, int cap_s,
    const unsigned* __restrict__ scur,
    unsigned* __restrict__ fcur, fvec4* __restrict__ fineSeg,
    unsigned* __restrict__ spillcur, fvec4* __restrict__ spillSeg)
{
    constexpr int SLICES = 8;
    const int super = blockIdx.x / SLICES;
    const int slice = blockIdx.x % SLICES;
    const unsigned n = min(scur[super], (unsigned)cap_s);
    const unsigned lo = (unsigned)(((unsigned long long)n * slice) / SLICES);
    const unsigned hi = (unsigned)(((unsigned long long)n * (slice + 1)) / SLICES);

    __shared__ unsigned cnt[NCHILD], base[NCHILD], off[NCHILD];
    const int t = threadIdx.x;
    if (t < NCHILD) { cnt[t] = 0; off[t] = 0; }
    __syncthreads();

    for (unsigned i = lo + t; i < hi; i += 256) {
        const fvec4 tp = superSeg[(size_t)super * cap_s + i];
        int s, c;
        fine_bin(tp.x, tp.y, tp.z, &s, &c);
        atomicAdd(&cnt[c], 1u);
    }
    __syncthreads();
    if (t < NCHILD) base[t] = atomicAdd(&fcur[super * NCHILD + t], cnt[t]);
    __syncthreads();
    for (unsigned i = lo + t; i < hi; i += 256) {
        const fvec4 tp = superSeg[(size_t)super * cap_s + i];
        int s, c;
        fine_bin(tp.x, tp.y, tp.z, &s, &c);
        const unsigned slot = base[c] + atomicAdd(&off[c], 1u);
        if (slot < (unsigned)CAP_F) {
            fineSeg[(size_t)(super * NCHILD + c) * CAP_F + slot] = tp;
        } else {
            const unsigned sp = atomicAdd(spillcur, 1u);
            if (sp < (unsigned)SPILL_CAP) spillSeg[sp] = tp;
        }
    }
}

// ---- B: per-fine-bin trilerp with LDS-staged latent footprint ---------------
// bin covers cells [bx*8, bx*8+7] x [by*8, by*8+7] x [bz*4, bz*4+3];
// staged rows [bx*8 .. +8] x [by*8 .. +8] x [bz*4 .. +4] = 9*9*5 = 405 rows.

__global__ __launch_bounds__(256, 6) void binB(
    const fvec4* __restrict__ fineSeg, const unsigned* __restrict__ fcur,
    const float* __restrict__ latents, float* __restrict__ out)
{
    __shared__ __align__(16) float lat[NROWS * 16];   // 25.9 KB

    const int fid = blockIdx.x;
    const int super = fid >> 7, c = fid & 127;
    const int bx = ((super >> 4) << 2)       | (c >> 5);         // [0,16)
    const int by = (((super >> 2) & 3) << 2) | ((c >> 3) & 3);   // [0,16)
    const int bz = ((super & 3) << 3)        | (c & 7);          // [0,32)
    const int t = threadIdx.x;

    // stage (clamped at 127; clamp rows are staged but never read)
    for (int u = t; u < NROWS * 4; u += 256) {
        const int q4 = u & 3, r = u >> 2;
        const int dz = r % 5, t2 = r / 5, dy = t2 % 9, dx = t2 / 9;
        const int gx = min(bx * 8 + dx, 127);
        const int gy = min(by * 8 + dy, 127);
        const int gz = min(bz * 4 + dz, 127);
        const fvec4 v = *reinterpret_cast<const fvec4*>(
            latents + ((size_t)(((gx << 7) | gy) << 7 | gz)) * LATENT_DIM + q4 * 4);
        const int sw = (q4 + r + (r >> 2)) & 3;     // bank swizzle
        *reinterpret_cast<fvec4*>(&lat[r * 16 + sw * 4]) = v;
    }
    __syncthreads();

    const unsigned n = min(fcur[fid], (unsigned)CAP_F);
    const int q = t & 3, lp = t >> 2;
    const fvec4* seg = fineSeg + (size_t)fid * CAP_F;

    fvec4 tp = (fvec4)(0.0f);
    if ((unsigned)lp < n) tp = seg[lp];

    for (unsigned i = lp; i < n; i += 64) {
        fvec4 nxt = tp;                             // prefetch next tuple
        if (i + 64 < n) nxt = seg[i + 64];

        const unsigned idx = __float_as_uint(tp.w);
        const float sxv = tp.x * SCALE, syv = tp.y * SCALE, szv = tp.z * SCALE;
        const float bxf = floorf(sxv), byf = floorf(syv), bzf = floorf(szv);
        const int lx = (int)bxf - bx * 8;           // [0,7]
        const int ly = (int)byf - by * 8;           // [0,7]
        const int lz = (int)bzf - bz * 4;           // [0,3]
        const float wbx = sxv - bxf, wby = syv - byf, wbz = szv - bzf;
        const float fx[2] = {1.0f - wbx, wbx};
        const float fy[2] = {1.0f - wby, wby};
        const float fz[2] = {1.0f - wbz, wbz};

        fvec4 acc = (fvec4)(0.0f);
        #pragma unroll
        for (int ox = 0; ox < 2; ++ox)
          #pragma unroll
          for (int oy = 0; oy < 2; ++oy)
            #pragma unroll
            for (int oz = 0; oz < 2; ++oz) {
                const int r = (lx + ox) * 45 + (ly + oy) * 5 + (lz + oz);
                const int sw = (q + r + (r >> 2)) & 3;
                const fvec4 f = *reinterpret_cast<const fvec4*>(&lat[r * 16 + sw * 4]);
                acc += (fx[ox] * fy[oy] * fz[oz]) * f;
            }

        *reinterpret_cast<fvec4*>(out + (size_t)idx * LATENT_DIM + q * 4) = acc;
        tp = nxt;
    }
}

// ---- spill cleanup (normally n == 0) ----------------------------------------

__global__ __launch_bounds__(256) void spillK(
    const fvec4* __restrict__ spillSeg, const unsigned* __restrict__ spillcur,
    const float* __restrict__ latents, float* __restrict__ out)
{
    const unsigned n = min(*spillcur, (unsigned)SPILL_CAP);
    for (unsigned i = blockIdx.x * 256 + threadIdx.x; i < n; i += gridDim.x * 256) {
        const fvec4 tp = spillSeg[i];
        const unsigned idx = __float_as_uint(tp.w);
        int cx[2], cy[2], cz[2]; float fx[2], fy[2], fz[2];
        corner_setup(tp.x * SCALE, tp.y * SCALE, tp.z * SCALE, cx, cy, cz, fx, fy, fz);
        #pragma unroll
        for (int q = 0; q < 4; ++q) {
            const fvec4 acc = trilerp_q(latents, cx, cy, cz, fx, fy, fz, q);
            *reinterpret_cast<fvec4*>(out + (size_t)idx * LATENT_DIM + q * 4) = acc;
        }
    }
}

// ---- fallback: direct version ----------------------------------------------

__global__ __launch_bounds__(256) void trilerp_direct(
    const float* __restrict__ pts, const float* __restrict__ latents,
    float* __restrict__ out, int n_pts)
{
    const int tid = blockIdx.x * blockDim.x + threadIdx.x;
    const int p = tid >> 2;
    const int q = tid & 3;
    if (p >= n_pts) return;
    int cx[2], cy[2], cz[2]; float fx[2], fy[2], fz[2];
    corner_setup(pts[3*p] * SCALE, pts[3*p+1] * SCALE, pts[3*p+2] * SCALE,
                 cx, cy, cz, fx, fy, fz);
    const fvec4 acc = trilerp_q(latents, cx, cy, cz, fx, fy, fz, q);
    *reinterpret_cast<fvec4*>(out + (size_t)p * LATENT_DIM + q * 4) = acc;
}

// ---- launch -----------------------------------------------------------------

extern "C" void kernel_launch(void* const* d_in, const int* in_sizes, int n_in,
                              void* d_out, int out_size, void* d_ws, size_t ws_size,
                              hipStream_t stream) {
    const float* pts     = (const float*)d_in[0];
    const float* latents = (const float*)d_in[1];
    float* out = (float*)d_out;
    const int n_pts = in_sizes[0] / 3;

    const int cap_s = (int)(((size_t)out_size * 4) / (NSUPER * 16));  // tuples/super seg

    if (ws_size < WS_NEEDED || cap_s * (size_t)NSUPER * 16 > (size_t)out_size * 4 ||
        (size_t)cap_s < (size_t)n_pts / 16) {
        const int total = n_pts * 4;
        trilerp_direct<<<(total + 255) / 256, 256, 0, stream>>>(pts, latents, out, n_pts);
        return;
    }

    unsigned* scur     = (unsigned*)((char*)d_ws + SCUR_OFF);
    unsigned* fcur     = (unsigned*)((char*)d_ws + FCUR_OFF);
    unsigned* spillcur = (unsigned*)((char*)d_ws + SPILLCUR_OFF);
    fvec4*    fineSeg  = (fvec4*)((char*)d_ws + FINE_OFF);
    fvec4*    spillSeg = (fvec4*)((char*)d_ws + SPILL_OFF);
    fvec4*    superSeg = (fvec4*)d_out;                 // reused as scratch

    hipMemsetAsync(d_ws, 0, CUR_BYTES, stream);
    binA1<<<256, 256, 0, stream>>>(pts, n_pts, scur, superSeg, cap_s,
                                   spillcur, spillSeg);
    binA2<<<NSUPER * 8, 256, 0, stream>>>(superSeg, cap_s, scur,
                                          fcur, fineSeg, spillcur, spillSeg);
    binB<<<NFINE, 256, 0, stream>>>(fineSeg, fcur, latents, out);
    spillK<<<16, 256, 0, stream>>>(spillSeg, spillcur, latents, out);
}

// Round 7
// 157.310 us; speedup vs baseline: 1.9031x; 1.0406x over previous
//
#include <hip/hip_runtime.h>

// Trilinear interpolation of a 128^3 x 16 latent grid at 2M random points.
// 3-phase spatial counting sort:
//   A1: counting-sort points into 64 super-bins (4x4x4 of fine bins), segments
//       in d_out (d_out fully overwritten by B afterwards).
//   A2: per super-bin, counting-sort its segment into 256 children -> 16384
//       fine bins (16x32x32; 8x4x4 grid cells each) in d_ws.
//   B : one block per fine bin; stage the bin's 9x5x5-row latent footprint
//       (225 rows, stride-20-dword layout, 18 KB -> 8 blocks/CU) into LDS;
//       all 8 gathers/point are LDS reads.
// Spill list + cleanup kernel guard the (>5 sigma) capacity overflow paths.

constexpr int   GRID_RES   = 128;
constexpr int   LATENT_DIM = 16;
constexpr float SCALE      = 126.0f;          // GRID_RES - 2

constexpr int NSUPER    = 64;                  // 4x4x4
constexpr int NCHILD    = 256;                 // 4x8x8 per super
constexpr int NFINE     = NSUPER * NCHILD;     // 16384 (16x32x32)
constexpr int CAP_F     = 192;                 // mean 128, sigma ~11.3
constexpr int SPILL_CAP = 16384;
constexpr int NROWS     = 9 * 5 * 5;           // 225 staged latent rows
constexpr int RS        = 20;                  // row stride in dwords (16B-aligned)

// d_ws layout
constexpr size_t SCUR_OFF     = 0;             // 64 u32
constexpr size_t FCUR_OFF     = 1024;          // 16384 u32
constexpr size_t SPILLCUR_OFF = 66560;         // 1 u32
constexpr size_t CUR_BYTES    = 69632;         // memset region
constexpr size_t FINE_OFF     = CUR_BYTES;
constexpr size_t FINE_BYTES   = (size_t)NFINE * CAP_F * 16;
constexpr size_t SPILL_OFF    = FINE_OFF + FINE_BYTES;
constexpr size_t WS_NEEDED    = SPILL_OFF + (size_t)SPILL_CAP * 16;

typedef float fvec4 __attribute__((ext_vector_type(4)));

// ---- helpers ----------------------------------------------------------------

__device__ __forceinline__ void fine_bin(float x, float y, float z,
                                         int* s, int* c) {
    const int lx = min(max((int)floorf(x * SCALE), 0), 125);
    const int ly = min(max((int)floorf(y * SCALE), 0), 125);
    const int lz = min(max((int)floorf(z * SCALE), 0), 125);
    const int fbx = lx >> 3;   // [0,16)
    const int fby = ly >> 2;   // [0,32)
    const int fbz = lz >> 2;   // [0,32)
    *s = ((fbx >> 2) << 4) | ((fby >> 3) << 2) | (fbz >> 3);           // [0,64)
    *c = ((fbx & 3) << 6) | ((fby & 7) << 3) | (fbz & 7);              // [0,256)
}

__device__ __forceinline__ void corner_setup(
    float sx, float sy, float sz,
    int cx[2], int cy[2], int cz[2],
    float fx[2], float fy[2], float fz[2])
{
    const float bx = floorf(sx), by = floorf(sy), bz = floorf(sz);
    const int ix = (int)bx, iy = (int)by, iz = (int)bz;
    const float wbx = sx - bx, wby = sy - by, wbz = sz - bz;
    cx[0] = min(max(ix,     0), GRID_RES - 1);
    cx[1] = min(max(ix + 1, 0), GRID_RES - 1);
    cy[0] = min(max(iy,     0), GRID_RES - 1);
    cy[1] = min(max(iy + 1, 0), GRID_RES - 1);
    cz[0] = min(max(iz,     0), GRID_RES - 1);
    cz[1] = min(max(iz + 1, 0), GRID_RES - 1);
    fx[0] = 1.0f - wbx; fx[1] = wbx;
    fy[0] = 1.0f - wby; fy[1] = wby;
    fz[0] = 1.0f - wbz; fz[1] = wbz;
}

__device__ __forceinline__ fvec4 trilerp_q(
    const float* __restrict__ latents,
    const int cx[2], const int cy[2], const int cz[2],
    const float fx[2], const float fy[2], const float fz[2], int q)
{
    fvec4 acc = (fvec4)(0.0f);
    #pragma unroll
    for (int ox = 0; ox < 2; ++ox)
      #pragma unroll
      for (int oy = 0; oy < 2; ++oy)
        #pragma unroll
        for (int oz = 0; oz < 2; ++oz) {
            const int flat = cx[ox] * (GRID_RES * GRID_RES) + cy[oy] * GRID_RES + cz[oz];
            const float w = fx[ox] * fy[oy] * fz[oz];
            const fvec4 f = *reinterpret_cast<const fvec4*>(
                latents + (size_t)flat * LATENT_DIM + q * 4);
            acc += w * f;
        }
    return acc;
}

// ---- A1: counting-sort into 64 super-bins (segments in d_out) ---------------

__global__ __launch_bounds__(256) void binA1(
    const float* __restrict__ pts, int n_pts,
    unsigned* __restrict__ scur, fvec4* __restrict__ superSeg, int cap_s,
    unsigned* __restrict__ spillcur, fvec4* __restrict__ spillSeg)
{
    __shared__ unsigned cnt[NSUPER], base[NSUPER], off[NSUPER];
    const int t = threadIdx.x;
    if (t < NSUPER) { cnt[t] = 0; off[t] = 0; }
    __syncthreads();

    const int chunk = (n_pts + gridDim.x - 1) / gridDim.x;
    const int lo = blockIdx.x * chunk;
    const int hi = min(lo + chunk, n_pts);

    for (int p = lo + t; p < hi; p += 256) {
        int s, c;
        fine_bin(pts[3*p], pts[3*p+1], pts[3*p+2], &s, &c);
        atomicAdd(&cnt[s], 1u);
    }
    __syncthreads();
    if (t < NSUPER) base[t] = atomicAdd(&scur[t], cnt[t]);
    __syncthreads();
    for (int p = lo + t; p < hi; p += 256) {
        const float x = pts[3*p], y = pts[3*p+1], z = pts[3*p+2];
        int s, c;
        fine_bin(x, y, z, &s, &c);
        const unsigned slot = base[s] + atomicAdd(&off[s], 1u);
        fvec4 tp; tp.x = x; tp.y = y; tp.z = z; tp.w = __uint_as_float((unsigned)p);
        if (slot < (unsigned)cap_s) {
            superSeg[(size_t)s * cap_s + slot] = tp;
        } else {                                   // ~impossible; keep correct
            const unsigned sp = atomicAdd(spillcur, 1u);
            if (sp < (unsigned)SPILL_CAP) spillSeg[sp] = tp;
        }
    }
}

// ---- A2: refine each super-bin into its 256 children ------------------------

__global__ __launch_bounds__(256) void binA2(
    const fvec4* __restrict__ superSeg, int cap_s,
    const unsigned* __restrict__ scur,
    unsigned* __restrict__ fcur, fvec4* __restrict__ fineSeg,
    unsigned* __restrict__ spillcur, fvec4* __restrict__ spillSeg)
{
    constexpr int SLICES = 8;
    const int super = blockIdx.x / SLICES;
    const int slice = blockIdx.x % SLICES;
    const unsigned n = min(scur[super], (unsigned)cap_s);
    const unsigned lo = (unsigned)(((unsigned long long)n * slice) / SLICES);
    const unsigned hi = (unsigned)(((unsigned long long)n * (slice + 1)) / SLICES);

    __shared__ unsigned cnt[NCHILD], base[NCHILD], off[NCHILD];
    const int t = threadIdx.x;
    cnt[t] = 0; off[t] = 0;          // NCHILD == blockDim
    __syncthreads();

    for (unsigned i = lo + t; i < hi; i += 256) {
        const fvec4 tp = superSeg[(size_t)super * cap_s + i];
        int s, c;
        fine_bin(tp.x, tp.y, tp.z, &s, &c);
        atomicAdd(&cnt[c], 1u);
    }
    __syncthreads();
    base[t] = atomicAdd(&fcur[super * NCHILD + t], cnt[t]);
    __syncthreads();
    for (unsigned i = lo + t; i < hi; i += 256) {
        const fvec4 tp = superSeg[(size_t)super * cap_s + i];
        int s, c;
        fine_bin(tp.x, tp.y, tp.z, &s, &c);
        const unsigned slot = base[c] + atomicAdd(&off[c], 1u);
        if (slot < (unsigned)CAP_F) {
            fineSeg[(size_t)(super * NCHILD + c) * CAP_F + slot] = tp;
        } else {
            const unsigned sp = atomicAdd(spillcur, 1u);
            if (sp < (unsigned)SPILL_CAP) spillSeg[sp] = tp;
        }
    }
}

// ---- B: per-fine-bin trilerp with LDS-staged latent footprint ---------------
// bin covers cells [bx*8,+8) x [by*4,+4) x [bz*4,+4);
// staged rows 9 x 5 x 5 = 225, LDS row stride 20 dwords (bank-spread, 16B-aligned).

__global__ __launch_bounds__(256, 8) void binB(
    const fvec4* __restrict__ fineSeg, const unsigned* __restrict__ fcur,
    const float* __restrict__ latents, float* __restrict__ out)
{
    __shared__ __align__(16) float lat[NROWS * RS];   // 18.0 KB

    const int fid = blockIdx.x;
    const int super = fid >> 8, c = fid & 255;
    const int bx = ((super >> 4) << 2)       | (c >> 6);         // [0,16)
    const int by = (((super >> 2) & 3) << 3) | ((c >> 3) & 7);   // [0,32)
    const int bz = ((super & 3) << 3)        | (c & 7);          // [0,32)
    const int t = threadIdx.x;

    // stage (clamped at 127; clamp rows are staged but never read)
    for (int u = t; u < NROWS * 4; u += 256) {
        const int q4 = u & 3, r = u >> 2;
        const int dz = r % 5, t2 = r / 5, dy = t2 % 5, dx = t2 / 5;
        const int gx = min(bx * 8 + dx, 127);
        const int gy = min(by * 4 + dy, 127);
        const int gz = min(bz * 4 + dz, 127);
        const fvec4 v = *reinterpret_cast<const fvec4*>(
            latents + ((size_t)(((gx << 7) | gy) << 7 | gz)) * LATENT_DIM + q4 * 4);
        *reinterpret_cast<fvec4*>(&lat[r * RS + q4 * 4]) = v;
    }
    __syncthreads();

    const unsigned n = min(fcur[fid], (unsigned)CAP_F);
    const int q = t & 3, lp = t >> 2;
    const fvec4* seg = fineSeg + (size_t)fid * CAP_F;

    fvec4 tp = (fvec4)(0.0f);
    if ((unsigned)lp < n) tp = seg[lp];

    for (unsigned i = lp; i < n; i += 64) {
        fvec4 nxt = tp;                             // prefetch next tuple
        if (i + 64 < n) nxt = seg[i + 64];

        const unsigned idx = __float_as_uint(tp.w);
        const float sxv = tp.x * SCALE, syv = tp.y * SCALE, szv = tp.z * SCALE;
        const float bxf = floorf(sxv), byf = floorf(syv), bzf = floorf(szv);
        const int lx = (int)bxf - bx * 8;           // [0,7]
        const int ly = (int)byf - by * 4;           // [0,3]
        const int lz = (int)bzf - bz * 4;           // [0,3]
        const float wbx = sxv - bxf, wby = syv - byf, wbz = szv - bzf;
        const float fx[2] = {1.0f - wbx, wbx};
        const float fy[2] = {1.0f - wby, wby};
        const float fz[2] = {1.0f - wbz, wbz};

        fvec4 acc = (fvec4)(0.0f);
        #pragma unroll
        for (int ox = 0; ox < 2; ++ox)
          #pragma unroll
          for (int oy = 0; oy < 2; ++oy)
            #pragma unroll
            for (int oz = 0; oz < 2; ++oz) {
                const int r = (lx + ox) * 25 + (ly + oy) * 5 + (lz + oz);
                const fvec4 f = *reinterpret_cast<const fvec4*>(&lat[r * RS + q * 4]);
                acc += (fx[ox] * fy[oy] * fz[oz]) * f;
            }

        *reinterpret_cast<fvec4*>(out + (size_t)idx * LATENT_DIM + q * 4) = acc;
        tp = nxt;
    }
}

// ---- spill cleanup (normally n == 0) ----------------------------------------

__global__ __launch_bounds__(256) void spillK(
    const fvec4* __restrict__ spillSeg, const unsigned* __restrict__ spillcur,
    const float* __restrict__ latents, float* __restrict__ out)
{
    const unsigned n = min(*spillcur, (unsigned)SPILL_CAP);
    for (unsigned i = blockIdx.x * 256 + threadIdx.x; i < n; i += gridDim.x * 256) {
        const fvec4 tp = spillSeg[i];
        const unsigned idx = __float_as_uint(tp.w);
        int cx[2], cy[2], cz[2]; float fx[2], fy[2], fz[2];
        corner_setup(tp.x * SCALE, tp.y * SCALE, tp.z * SCALE, cx, cy, cz, fx, fy, fz);
        #pragma unroll
        for (int q = 0; q < 4; ++q) {
            const fvec4 acc = trilerp_q(latents, cx, cy, cz, fx, fy, fz, q);
            *reinterpret_cast<fvec4*>(out + (size_t)idx * LATENT_DIM + q * 4) = acc;
        }
    }
}

// ---- fallback: direct version ----------------------------------------------

__global__ __launch_bounds__(256) void trilerp_direct(
    const float* __restrict__ pts, const float* __restrict__ latents,
    float* __restrict__ out, int n_pts)
{
    const int tid = blockIdx.x * blockDim.x + threadIdx.x;
    const int p = tid >> 2;
    const int q = tid & 3;
    if (p >= n_pts) return;
    int cx[2], cy[2], cz[2]; float fx[2], fy[2], fz[2];
    corner_setup(pts[3*p] * SCALE, pts[3*p+1] * SCALE, pts[3*p+2] * SCALE,
                 cx, cy, cz, fx, fy, fz);
    const fvec4 acc = trilerp_q(latents, cx, cy, cz, fx, fy, fz, q);
    *reinterpret_cast<fvec4*>(out + (size_t)p * LATENT_DIM + q * 4) = acc;
}

// ---- launch -----------------------------------------------------------------

extern "C" void kernel_launch(void* const* d_in, const int* in_sizes, int n_in,
                              void* d_out, int out_size, void* d_ws, size_t ws_size,
                              hipStream_t stream) {
    const float* pts     = (const float*)d_in[0];
    const float* latents = (const float*)d_in[1];
    float* out = (float*)d_out;
    const int n_pts = in_sizes[0] / 3;

    const int cap_s = (int)(((size_t)out_size * 4) / (NSUPER * 16));  // tuples/super seg

    if (ws_size < WS_NEEDED || cap_s * (size_t)NSUPER * 16 > (size_t)out_size * 4 ||
        (size_t)cap_s < (size_t)n_pts / 16) {
        const int total = n_pts * 4;
        trilerp_direct<<<(total + 255) / 256, 256, 0, stream>>>(pts, latents, out, n_pts);
        return;
    }

    unsigned* scur     = (unsigned*)((char*)d_ws + SCUR_OFF);
    unsigned* fcur     = (unsigned*)((char*)d_ws + FCUR_OFF);
    unsigned* spillcur = (unsigned*)((char*)d_ws + SPILLCUR_OFF);
    fvec4*    fineSeg  = (fvec4*)((char*)d_ws + FINE_OFF);
    fvec4*    spillSeg = (fvec4*)((char*)d_ws + SPILL_OFF);
    fvec4*    superSeg = (fvec4*)d_out;                 // reused as scratch

    hipMemsetAsync(d_ws, 0, CUR_BYTES, stream);
    binA1<<<512, 256, 0, stream>>>(pts, n_pts, scur, superSeg, cap_s,
                                   spillcur, spillSeg);
    binA2<<<NSUPER * 8, 256, 0, stream>>>(superSeg, cap_s, scur,
                                          fcur, fineSeg, spillcur, spillSeg);
    binB<<<NFINE, 256, 0, stream>>>(fineSeg, fcur, latents, out);
    spillK<<<16, 256, 0, stream>>>(spillSeg, spillcur, latents, out);
}

// Round 8
// 153.367 us; speedup vs baseline: 1.9520x; 1.0257x over previous
//
#include <hip/hip_runtime.h>

// Trilinear interpolation of a 128^3 x 16 latent grid at 2M random points.
// 3-phase spatial counting sort:
//   A1: counting-sort points into 64 super-bins (4x4x4 of fine bins), segments
//       in d_out (d_out fully overwritten by B afterwards).
//   A2: per super-bin, counting-sort its segment into 256 children -> 16384
//       fine bins (16x32x32; 8x4x4 grid cells each) in d_ws.
//   B : one block per fine bin; issue the thread's <=3 tuple loads EARLY (T14),
//       stage the bin's 9x5x5-row latent footprint (225 rows, stride-20-dword,
//       18 KB -> 8 blocks/CU) into LDS, then compute 3 independent chains.
// Spill list + cleanup kernel guard the (>5 sigma) capacity overflow paths.

constexpr int   GRID_RES   = 128;
constexpr int   LATENT_DIM = 16;
constexpr float SCALE      = 126.0f;          // GRID_RES - 2

constexpr int NSUPER    = 64;                  // 4x4x4
constexpr int NCHILD    = 256;                 // 4x8x8 per super
constexpr int NFINE     = NSUPER * NCHILD;     // 16384 (16x32x32)
constexpr int CAP_F     = 192;                 // mean 128, sigma ~11.3
constexpr int SPILL_CAP = 16384;
constexpr int NROWS     = 9 * 5 * 5;           // 225 staged latent rows
constexpr int RS        = 20;                  // row stride in dwords (16B-aligned)

// d_ws layout
constexpr size_t SCUR_OFF     = 0;             // 64 u32
constexpr size_t FCUR_OFF     = 1024;          // 16384 u32
constexpr size_t SPILLCUR_OFF = 66560;         // 1 u32
constexpr size_t CUR_BYTES    = 69632;         // memset region
constexpr size_t FINE_OFF     = CUR_BYTES;
constexpr size_t FINE_BYTES   = (size_t)NFINE * CAP_F * 16;
constexpr size_t SPILL_OFF    = FINE_OFF + FINE_BYTES;
constexpr size_t WS_NEEDED    = SPILL_OFF + (size_t)SPILL_CAP * 16;

typedef float fvec4 __attribute__((ext_vector_type(4)));

// ---- helpers ----------------------------------------------------------------

__device__ __forceinline__ void fine_bin(float x, float y, float z,
                                         int* s, int* c) {
    const int lx = min(max((int)floorf(x * SCALE), 0), 125);
    const int ly = min(max((int)floorf(y * SCALE), 0), 125);
    const int lz = min(max((int)floorf(z * SCALE), 0), 125);
    const int fbx = lx >> 3;   // [0,16)
    const int fby = ly >> 2;   // [0,32)
    const int fbz = lz >> 2;   // [0,32)
    *s = ((fbx >> 2) << 4) | ((fby >> 3) << 2) | (fbz >> 3);           // [0,64)
    *c = ((fbx & 3) << 6) | ((fby & 7) << 3) | (fbz & 7);              // [0,256)
}

__device__ __forceinline__ void corner_setup(
    float sx, float sy, float sz,
    int cx[2], int cy[2], int cz[2],
    float fx[2], float fy[2], float fz[2])
{
    const float bx = floorf(sx), by = floorf(sy), bz = floorf(sz);
    const int ix = (int)bx, iy = (int)by, iz = (int)bz;
    const float wbx = sx - bx, wby = sy - by, wbz = sz - bz;
    cx[0] = min(max(ix,     0), GRID_RES - 1);
    cx[1] = min(max(ix + 1, 0), GRID_RES - 1);
    cy[0] = min(max(iy,     0), GRID_RES - 1);
    cy[1] = min(max(iy + 1, 0), GRID_RES - 1);
    cz[0] = min(max(iz,     0), GRID_RES - 1);
    cz[1] = min(max(iz + 1, 0), GRID_RES - 1);
    fx[0] = 1.0f - wbx; fx[1] = wbx;
    fy[0] = 1.0f - wby; fy[1] = wby;
    fz[0] = 1.0f - wbz; fz[1] = wbz;
}

__device__ __forceinline__ fvec4 trilerp_q(
    const float* __restrict__ latents,
    const int cx[2], const int cy[2], const int cz[2],
    const float fx[2], const float fy[2], const float fz[2], int q)
{
    fvec4 acc = (fvec4)(0.0f);
    #pragma unroll
    for (int ox = 0; ox < 2; ++ox)
      #pragma unroll
      for (int oy = 0; oy < 2; ++oy)
        #pragma unroll
        for (int oz = 0; oz < 2; ++oz) {
            const int flat = cx[ox] * (GRID_RES * GRID_RES) + cy[oy] * GRID_RES + cz[oz];
            const float w = fx[ox] * fy[oy] * fz[oz];
            const fvec4 f = *reinterpret_cast<const fvec4*>(
                latents + (size_t)flat * LATENT_DIM + q * 4);
            acc += w * f;
        }
    return acc;
}

// ---- A1: counting-sort into 64 super-bins (segments in d_out) ---------------

__global__ __launch_bounds__(256) void binA1(
    const float* __restrict__ pts, int n_pts,
    unsigned* __restrict__ scur, fvec4* __restrict__ superSeg, int cap_s,
    unsigned* __restrict__ spillcur, fvec4* __restrict__ spillSeg)
{
    __shared__ unsigned cnt[NSUPER], base[NSUPER], off[NSUPER];
    const int t = threadIdx.x;
    if (t < NSUPER) { cnt[t] = 0; off[t] = 0; }
    __syncthreads();

    const int chunk = (n_pts + gridDim.x - 1) / gridDim.x;
    const int lo = blockIdx.x * chunk;
    const int hi = min(lo + chunk, n_pts);

    for (int p = lo + t; p < hi; p += 256) {
        int s, c;
        fine_bin(pts[3*p], pts[3*p+1], pts[3*p+2], &s, &c);
        atomicAdd(&cnt[s], 1u);
    }
    __syncthreads();
    if (t < NSUPER) base[t] = atomicAdd(&scur[t], cnt[t]);
    __syncthreads();
    for (int p = lo + t; p < hi; p += 256) {
        const float x = pts[3*p], y = pts[3*p+1], z = pts[3*p+2];
        int s, c;
        fine_bin(x, y, z, &s, &c);
        const unsigned slot = base[s] + atomicAdd(&off[s], 1u);
        fvec4 tp; tp.x = x; tp.y = y; tp.z = z; tp.w = __uint_as_float((unsigned)p);
        if (slot < (unsigned)cap_s) {
            superSeg[(size_t)s * cap_s + slot] = tp;
        } else {                                   // ~impossible; keep correct
            const unsigned sp = atomicAdd(spillcur, 1u);
            if (sp < (unsigned)SPILL_CAP) spillSeg[sp] = tp;
        }
    }
}

// ---- A2: refine each super-bin into its 256 children ------------------------

__global__ __launch_bounds__(256) void binA2(
    const fvec4* __restrict__ superSeg, int cap_s,
    const unsigned* __restrict__ scur,
    unsigned* __restrict__ fcur, fvec4* __restrict__ fineSeg,
    unsigned* __restrict__ spillcur, fvec4* __restrict__ spillSeg)
{
    constexpr int SLICES = 8;
    const int super = blockIdx.x / SLICES;
    const int slice = blockIdx.x % SLICES;
    const unsigned n = min(scur[super], (unsigned)cap_s);
    const unsigned lo = (unsigned)(((unsigned long long)n * slice) / SLICES);
    const unsigned hi = (unsigned)(((unsigned long long)n * (slice + 1)) / SLICES);

    __shared__ unsigned cnt[NCHILD], base[NCHILD], off[NCHILD];
    const int t = threadIdx.x;
    cnt[t] = 0; off[t] = 0;          // NCHILD == blockDim
    __syncthreads();

    for (unsigned i = lo + t; i < hi; i += 256) {
        const fvec4 tp = superSeg[(size_t)super * cap_s + i];
        int s, c;
        fine_bin(tp.x, tp.y, tp.z, &s, &c);
        atomicAdd(&cnt[c], 1u);
    }
    __syncthreads();
    base[t] = atomicAdd(&fcur[super * NCHILD + t], cnt[t]);
    __syncthreads();
    for (unsigned i = lo + t; i < hi; i += 256) {
        const fvec4 tp = superSeg[(size_t)super * cap_s + i];
        int s, c;
        fine_bin(tp.x, tp.y, tp.z, &s, &c);
        const unsigned slot = base[c] + atomicAdd(&off[c], 1u);
        if (slot < (unsigned)CAP_F) {
            fineSeg[(size_t)(super * NCHILD + c) * CAP_F + slot] = tp;
        } else {
            const unsigned sp = atomicAdd(spillcur, 1u);
            if (sp < (unsigned)SPILL_CAP) spillSeg[sp] = tp;
        }
    }
}

// ---- B: per-fine-bin trilerp with LDS-staged latent footprint ---------------
// bin covers cells [bx*8,+8) x [by*4,+4) x [bz*4,+4);
// staged rows 9 x 5 x 5 = 225, LDS row stride 20 dwords (bank-spread, 16B-aligned).
// Tuple loads are issued BEFORE staging so their latency hides under it (T14).

__global__ __launch_bounds__(256, 8) void binB(
    const fvec4* __restrict__ fineSeg, const unsigned* __restrict__ fcur,
    const float* __restrict__ latents, float* __restrict__ out)
{
    __shared__ __align__(16) float lat[NROWS * RS];   // 18.0 KB

    const int fid = blockIdx.x;
    const int super = fid >> 8, c = fid & 255;
    const int bx = ((super >> 4) << 2)       | (c >> 6);         // [0,16)
    const int by = (((super >> 2) & 3) << 3) | ((c >> 3) & 7);   // [0,32)
    const int bz = ((super & 3) << 3)        | (c & 7);          // [0,32)
    const int t = threadIdx.x;
    const int q = t & 3, lp = t >> 2;

    // ---- issue tuple loads early: latency overlaps the staging phase --------
    const int n = (int)min(fcur[fid], (unsigned)CAP_F);   // n <= 192 = 3*64
    const fvec4* seg = fineSeg + (size_t)fid * CAP_F;

    fvec4 tp0 = (fvec4)(0.0f), tp1 = (fvec4)(0.0f), tp2 = (fvec4)(0.0f);
    if (lp       < n) tp0 = __builtin_nontemporal_load(&seg[lp]);
    if (lp + 64  < n) tp1 = __builtin_nontemporal_load(&seg[lp + 64]);
    if (lp + 128 < n) tp2 = __builtin_nontemporal_load(&seg[lp + 128]);

    // ---- stage latent tile (clamped at 127; clamp rows staged, never read) --
    #pragma unroll
    for (int k = 0; k < 4; ++k) {
        const int u = t + k * 256;
        if (u < NROWS * 4) {
            const int q4 = u & 3, r = u >> 2;
            const int dz = r % 5, t2 = r / 5, dy = t2 % 5, dx = t2 / 5;
            const int gx = min(bx * 8 + dx, 127);
            const int gy = min(by * 4 + dy, 127);
            const int gz = min(bz * 4 + dz, 127);
            const fvec4 v = *reinterpret_cast<const fvec4*>(
                latents + ((size_t)(((gx << 7) | gy) << 7 | gz)) * LATENT_DIM + q4 * 4);
            *reinterpret_cast<fvec4*>(&lat[r * RS + q4 * 4]) = v;
        }
    }
    __syncthreads();

    // ---- three independent compute chains (ILP) -----------------------------
    #pragma unroll
    for (int k = 0; k < 3; ++k) {
        if (lp + k * 64 < n) {
            const fvec4 tp = (k == 0) ? tp0 : (k == 1) ? tp1 : tp2;
            const unsigned idx = __float_as_uint(tp.w);
            const float sxv = tp.x * SCALE, syv = tp.y * SCALE, szv = tp.z * SCALE;
            const float bxf = floorf(sxv), byf = floorf(syv), bzf = floorf(szv);
            const int lx = (int)bxf - bx * 8;           // [0,7]
            const int ly = (int)byf - by * 4;           // [0,3]
            const int lz = (int)bzf - bz * 4;           // [0,3]
            const float wbx = sxv - bxf, wby = syv - byf, wbz = szv - bzf;
            const float fx[2] = {1.0f - wbx, wbx};
            const float fy[2] = {1.0f - wby, wby};
            const float fz[2] = {1.0f - wbz, wbz};

            fvec4 acc = (fvec4)(0.0f);
            #pragma unroll
            for (int ox = 0; ox < 2; ++ox)
              #pragma unroll
              for (int oy = 0; oy < 2; ++oy)
                #pragma unroll
                for (int oz = 0; oz < 2; ++oz) {
                    const int r = (lx + ox) * 25 + (ly + oy) * 5 + (lz + oz);
                    const fvec4 f = *reinterpret_cast<const fvec4*>(&lat[r * RS + q * 4]);
                    acc += (fx[ox] * fy[oy] * fz[oz]) * f;
                }

            __builtin_nontemporal_store(acc,
                reinterpret_cast<fvec4*>(out + (size_t)idx * LATENT_DIM + q * 4));
        }
    }
}

// ---- spill cleanup (normally n == 0) ----------------------------------------

__global__ __launch_bounds__(256) void spillK(
    const fvec4* __restrict__ spillSeg, const unsigned* __restrict__ spillcur,
    const float* __restrict__ latents, float* __restrict__ out)
{
    const unsigned n = min(*spillcur, (unsigned)SPILL_CAP);
    for (unsigned i = blockIdx.x * 256 + threadIdx.x; i < n; i += gridDim.x * 256) {
        const fvec4 tp = spillSeg[i];
        const unsigned idx = __float_as_uint(tp.w);
        int cx[2], cy[2], cz[2]; float fx[2], fy[2], fz[2];
        corner_setup(tp.x * SCALE, tp.y * SCALE, tp.z * SCALE, cx, cy, cz, fx, fy, fz);
        #pragma unroll
        for (int q = 0; q < 4; ++q) {
            const fvec4 acc = trilerp_q(latents, cx, cy, cz, fx, fy, fz, q);
            *reinterpret_cast<fvec4*>(out + (size_t)idx * LATENT_DIM + q * 4) = acc;
        }
    }
}

// ---- fallback: direct version ----------------------------------------------

__global__ __launch_bounds__(256) void trilerp_direct(
    const float* __restrict__ pts, const float* __restrict__ latents,
    float* __restrict__ out, int n_pts)
{
    const int tid = blockIdx.x * blockDim.x + threadIdx.x;
    const int p = tid >> 2;
    const int q = tid & 3;
    if (p >= n_pts) return;
    int cx[2], cy[2], cz[2]; float fx[2], fy[2], fz[2];
    corner_setup(pts[3*p] * SCALE, pts[3*p+1] * SCALE, pts[3*p+2] * SCALE,
                 cx, cy, cz, fx, fy, fz);
    const fvec4 acc = trilerp_q(latents, cx, cy, cz, fx, fy, fz, q);
    *reinterpret_cast<fvec4*>(out + (size_t)p * LATENT_DIM + q * 4) = acc;
}

// ---- launch -----------------------------------------------------------------

extern "C" void kernel_launch(void* const* d_in, const int* in_sizes, int n_in,
                              void* d_out, int out_size, void* d_ws, size_t ws_size,
                              hipStream_t stream) {
    const float* pts     = (const float*)d_in[0];
    const float* latents = (const float*)d_in[1];
    float* out = (float*)d_out;
    const int n_pts = in_sizes[0] / 3;

    const int cap_s = (int)(((size_t)out_size * 4) / (NSUPER * 16));  // tuples/super seg

    if (ws_size < WS_NEEDED || cap_s * (size_t)NSUPER * 16 > (size_t)out_size * 4 ||
        (size_t)cap_s < (size_t)n_pts / 16) {
        const int total = n_pts * 4;
        trilerp_direct<<<(total + 255) / 256, 256, 0, stream>>>(pts, latents, out, n_pts);
        return;
    }

    unsigned* scur     = (unsigned*)((char*)d_ws + SCUR_OFF);
    unsigned* fcur     = (unsigned*)((char*)d_ws + FCUR_OFF);
    unsigned* spillcur = (unsigned*)((char*)d_ws + SPILLCUR_OFF);
    fvec4*    fineSeg  = (fvec4*)((char*)d_ws + FINE_OFF);
    fvec4*    spillSeg = (fvec4*)((char*)d_ws + SPILL_OFF);
    fvec4*    superSeg = (fvec4*)d_out;                 // reused as scratch

    hipMemsetAsync(d_ws, 0, CUR_BYTES, stream);
    binA1<<<512, 256, 0, stream>>>(pts, n_pts, scur, superSeg, cap_s,
                                   spillcur, spillSeg);
    binA2<<<NSUPER * 8, 256, 0, stream>>>(superSeg, cap_s, scur,
                                          fcur, fineSeg, spillcur, spillSeg);
    binB<<<NFINE, 256, 0, stream>>>(fineSeg, fcur, latents, out);
    spillK<<<16, 256, 0, stream>>>(spillSeg, spillcur, latents, out);
}